// Round 5
// baseline (438.598 us; speedup 1.0000x reference)
//
#include <hip/hip_runtime.h>
#include <hip/hip_bf16.h>

// CRF NLL + argmax, B=2048, T=1024, K=8.
// p_t = D_t E^T p_{t-1};  E = exp(transitions), pinned in SGPRs via
// readfirstlane (round-4 lesson: per-lane E[64] spills at VGPR budget ->
// 64 memory reads per step -> VALUBusy 6%).
// NC=64 even-split chunks/batch; persistent waves + atomic task queue
// (task = 8 chunks, 8-lane group each, lane k = column k). Coalesced float4
// emission loads (4 steps per 8-lane group), exp shared via width-8 shuffles.
// Combine: block-per-batch LDS tree (6 levels of scale-aware 8x8 products).

namespace {

constexpr int B = 2048;
constexpr int T = 1024;
constexpr int NC = 64;                 // chunks per batch
constexpr int NTASK = B * (NC / 8);    // 16384 wave-tasks

__device__ __forceinline__ float max8(const float* a) {
  return fmaxf(fmaxf(fmaxf(a[0], a[1]), fmaxf(a[2], a[3])),
               fmaxf(fmaxf(a[4], a[5]), fmaxf(a[6], a[7])));
}

__device__ __forceinline__ float uniform_f(float v) {
  return __int_as_float(__builtin_amdgcn_readfirstlane(__float_as_int(v)));
}

// ---------------------------------------------------------------------------
// Kernel 0: init — zero wsNum/out[0]/queue counter, precompute expE.
// ---------------------------------------------------------------------------
__global__ void init_kernel(const float* __restrict__ trans,
                            float* __restrict__ expE,
                            float* __restrict__ ws_num, int* __restrict__ ctr,
                            float* __restrict__ out0) {
  int i = threadIdx.x;
  for (int r = i; r < B; r += 256) ws_num[r] = 0.0f;
  if (i < 64) expE[i] = __expf(trans[i]);
  if (i == 64) *ctr = 0;
  if (i == 65) *out0 = 0.0f;
}

// ---------------------------------------------------------------------------
// Kernel 1: 4 timesteps/thread: argmax prediction + numerator partials.
// ---------------------------------------------------------------------------
__global__ __launch_bounds__(256) void pred_num_kernel(
    const float* __restrict__ log_p, const float* __restrict__ score,
    const float* __restrict__ trans, const float* __restrict__ start_tr,
    const float* __restrict__ end_tr, const int* __restrict__ tags,
    const int* __restrict__ seq_l, float* __restrict__ out_pred,
    float* __restrict__ ws_num) {
  int tid = blockIdx.x * blockDim.x + threadIdx.x;
  int g0 = tid << 2;
  int b = g0 >> 10;
  int t0 = g0 & (T - 1);
  int L = seq_l[b];

  const float4* lp = reinterpret_cast<const float4*>(log_p) + (g0 << 1);
  float4 u[8];
#pragma unroll
  for (int r = 0; r < 8; ++r) u[r] = lp[r];
  int4 tg4 = *reinterpret_cast<const int4*>(tags + g0);
  int tg[4] = {tg4.x, tg4.y, tg4.z, tg4.w};
  int prev0 = (t0 == 0) ? 0 : tags[g0 - 1];

  float contrib = 0.0f;
#pragma unroll
  for (int r = 0; r < 4; ++r) {
    float v[8] = {u[2 * r].x, u[2 * r].y, u[2 * r].z, u[2 * r].w,
                  u[2 * r + 1].x, u[2 * r + 1].y, u[2 * r + 1].z,
                  u[2 * r + 1].w};
    int best = 0;
    float bv = v[0];
#pragma unroll
    for (int j = 1; j < 8; ++j) {
      if (v[j] > bv) { bv = v[j]; best = j; }
    }
    int t = t0 + r;
    bool act = (t < L);
    out_pred[g0 + r] = act ? (float)best : 0.0f;
    if (act) {
      int tgr = tg[r];
      float csum = score[(size_t)(g0 + r) * 8 + tgr];
      if (t == 0)
        csum += start_tr[tgr];
      else
        csum += trans[((r == 0) ? prev0 : tg[r - 1]) * 8 + tgr];
      if (t == L - 1) csum += end_tr[tgr];
      contrib += csum;
    }
  }
#pragma unroll
  for (int off = 32; off >= 1; off >>= 1) contrib += __shfl_down(contrib, off);
  if ((threadIdx.x & 63) == 0) atomicAdd(&ws_num[b], contrib);
}

// ---------------------------------------------------------------------------
// Kernel 2: persistent-wave chunk kernel, E pinned to SGPRs.
// ---------------------------------------------------------------------------
__global__ __launch_bounds__(256) void chunk_kernel(
    const float* __restrict__ score, const float* __restrict__ expE,
    const int* __restrict__ seq_l, float* __restrict__ wsA,
    float* __restrict__ wsS, int* __restrict__ ctr) {
  // E is wave-uniform: force into SGPRs (readfirstlane). 64 scalars.
  float E[64];
#pragma unroll
  for (int i = 0; i < 64; ++i) E[i] = uniform_f(expE[i]);

  int lane = threadIdx.x & 63;
  int grp = lane >> 3;
  int k = lane & 7;

  for (;;) {
    int tv = 0;
    if (lane == 0) tv = atomicAdd(ctr, 1);
    int task = __shfl(tv, 0);
    if (task >= NTASK) break;
    int b = task >> 3;
    int oct = task & 7;
    int c = oct * 8 + grp;

    int S = seq_l[b] - 1;
    int ts = 1 + ((S * c) >> 6);
    int te = 1 + ((S * (c + 1)) >> 6);
    int nblk = (te - ts + 3) >> 2;

    float a[8];
#pragma unroll
    for (int j = 0; j < 8; ++j) a[j] = (j == k) ? 1.0f : 0.0f;
    float sig = 0.0f;

    const float* rowb = score + (size_t)b * T * 8;
    int t = ts;
    float4 cur;
    if (nblk > 0) {
      int tl = min(t + (k >> 1), T - 1);
      cur = *reinterpret_cast<const float4*>(rowb + tl * 8 + (k & 1) * 4);
    }
    for (int blk = 0; blk < nblk; ++blk) {
      float4 nxt = cur;
      if (blk + 1 < nblk) {
        int tl = min(t + 4 + (k >> 1), T - 1);
        nxt = *reinterpret_cast<const float4*>(rowb + tl * 8 + (k & 1) * 4);
      }
      float4 ex = make_float4(__expf(cur.x), __expf(cur.y), __expf(cur.z),
                              __expf(cur.w));
      int nst = min(4, te - t);
#pragma unroll
      for (int s = 0; s < 4; ++s) {
        if (s >= nst) break;
        float em[8];
        em[0] = __shfl(ex.x, 2 * s, 8);
        em[1] = __shfl(ex.y, 2 * s, 8);
        em[2] = __shfl(ex.z, 2 * s, 8);
        em[3] = __shfl(ex.w, 2 * s, 8);
        em[4] = __shfl(ex.x, 2 * s + 1, 8);
        em[5] = __shfl(ex.y, 2 * s + 1, 8);
        em[6] = __shfl(ex.z, 2 * s + 1, 8);
        em[7] = __shfl(ex.w, 2 * s + 1, 8);
        float na[8];
#pragma unroll
        for (int j = 0; j < 8; ++j) {
          float acc = E[0 * 8 + j] * a[0];
#pragma unroll
          for (int i = 1; i < 8; ++i) acc = fmaf(E[i * 8 + j], a[i], acc);
          na[j] = em[j] * acc;
        }
#pragma unroll
        for (int j = 0; j < 8; ++j) a[j] = na[j];
      }
      if (blk & 1) {  // rescale every 8 steps
        float mm = max8(a);
        float r = __builtin_amdgcn_rcpf(mm);
#pragma unroll
        for (int j = 0; j < 8; ++j) a[j] *= r;
        sig += __logf(mm);
      }
      cur = nxt;
      t += 4;
    }
    {  // final normalize (len==0 -> identity, mm==1, sig==0)
      float mm = max8(a);
      if (mm > 0.0f) {
        float r = __builtin_amdgcn_rcpf(mm);
#pragma unroll
        for (int j = 0; j < 8; ++j) a[j] *= r;
        sig += __logf(mm);
      }
    }

    float* Ao = wsA + (size_t)(b * NC + c) * 64;
#pragma unroll
    for (int j = 0; j < 8; ++j) Ao[j * 8 + k] = a[j];  // row-major
    wsS[(b * NC + c) * 8 + k] = sig;
  }
}

// ---------------------------------------------------------------------------
// Kernel 3: combine — block per batch, LDS tree of scale-aware products.
// ---------------------------------------------------------------------------
__global__ __launch_bounds__(256) void combine_kernel(
    const float* __restrict__ score, const float* __restrict__ start_tr,
    const float* __restrict__ end_tr, const float* __restrict__ wsA,
    const float* __restrict__ wsS, const float* __restrict__ ws_num,
    float* __restrict__ out_loss) {
  __shared__ float sm[96 * 73];
  int b = blockIdx.x;
  int tid = threadIdx.x;
  const float* Ab = wsA + (size_t)b * NC * 64;
  const float* Sb = wsS + (size_t)b * NC * 8;

#pragma unroll
  for (int r = 0; r < 4; ++r) {
    int vi = tid + r * 256;
    int g = vi * 4;
    int c = g >> 6, rem = g & 63;
    float4 q = reinterpret_cast<const float4*>(Ab)[vi];
    float* dst = &sm[c * 73 + rem];
    dst[0] = q.x; dst[1] = q.y; dst[2] = q.z; dst[3] = q.w;
  }
#pragma unroll
  for (int r = 0; r < 2; ++r) {
    int gi = tid + r * 256;
    sm[(gi >> 3) * 73 + 64 + (gi & 7)] = Sb[gi];
  }
  __syncthreads();

  float* bufB = &sm[64 * 73];
  int p = tid >> 3, k = tid & 7;
#pragma unroll
  for (int lvl = 1; lvl <= 6; ++lvl) {
    int nprod = NC >> lvl;
    float* inb = (lvl & 1) ? sm : bufB;
    float* outb = (lvl & 1) ? bufB : sm;
    if (p < nprod) {
      const float* M0 = inb + (size_t)(2 * p) * 73;      // earlier (right)
      const float* M1 = inb + (size_t)(2 * p + 1) * 73;  // later (left)
      float s1[8];
#pragma unroll
      for (int i = 0; i < 8; ++i) s1[i] = M1[64 + i];
      float m = max8(s1);
      float w[8];
#pragma unroll
      for (int i = 0; i < 8; ++i) w[i] = M0[i * 8 + k] * __expf(s1[i] - m);
      float u[8];
#pragma unroll
      for (int j = 0; j < 8; ++j) {
        float acc = M1[j * 8 + 0] * w[0];
#pragma unroll
        for (int i = 1; i < 8; ++i) acc = fmaf(M1[j * 8 + i], w[i], acc);
        u[j] = acc;
      }
      float mm = fmaxf(max8(u), 1e-37f);
      float rc = __builtin_amdgcn_rcpf(mm);
      float* D = outb + (size_t)p * 73;
#pragma unroll
      for (int j = 0; j < 8; ++j) D[j * 8 + k] = u[j] * rc;
      D[64 + k] = M0[64 + k] + m + __logf(mm);
    }
    __syncthreads();
  }

  if (tid < 8) {
    int j = tid;
    float p0 = __expf(start_tr[j] + score[(size_t)b * T * 8 + j]);
    float m0 = p0;
#pragma unroll
    for (int m = 1; m < 8; m <<= 1) m0 = fmaxf(m0, __shfl_xor(m0, m, 8));
    float p0n = p0 * __builtin_amdgcn_rcpf(m0);
    float p0a[8];
#pragma unroll
    for (int i = 0; i < 8; ++i) p0a[i] = __shfl(p0n, i, 8);
    float sM[8];
#pragma unroll
    for (int i = 0; i < 8; ++i) sM[i] = sm[64 + i];
    float mS = max8(sM);
    float inner = 0.0f;
#pragma unroll
    for (int i = 0; i < 8; ++i)
      inner = fmaf(sm[j * 8 + i], __expf(sM[i] - mS) * p0a[i], inner);
    float term = inner * __expf(end_tr[j]);
#pragma unroll
    for (int m = 1; m < 8; m <<= 1) term += __shfl_xor(term, m, 8);
    if (j == 0) {
      float logz = __logf(m0) + mS + __logf(term);
      atomicAdd(out_loss, (logz - ws_num[b]) * (1.0f / (float)B));
    }
  }
}

}  // namespace

extern "C" void kernel_launch(void* const* d_in, const int* in_sizes, int n_in,
                              void* d_out, int out_size, void* d_ws,
                              size_t ws_size, hipStream_t stream) {
  const float* log_p = (const float*)d_in[0];
  const float* score = (const float*)d_in[1];
  const float* trans = (const float*)d_in[2];
  const float* start_tr = (const float*)d_in[3];
  const float* end_tr = (const float*)d_in[4];
  const int* tags = (const int*)d_in[5];
  const int* seq_l = (const int*)d_in[6];
  float* out = (float*)d_out;  // out[0]=loss, out[1..]=pred_idx

  float* wsA = (float*)d_ws;                  // B*NC*64
  float* wsS = wsA + (size_t)B * NC * 64;     // B*NC*8
  float* wsNum = wsS + (size_t)B * NC * 8;    // B
  float* wsExpE = wsNum + B;                  // 64
  int* wsCtr = (int*)(wsExpE + 64);           // 1

  init_kernel<<<1, 256, 0, stream>>>(trans, wsExpE, wsNum, wsCtr, out);
  pred_num_kernel<<<(B * T / 4) / 256, 256, 0, stream>>>(
      log_p, score, trans, start_tr, end_tr, tags, seq_l, out + 1, wsNum);
  chunk_kernel<<<1024, 256, 0, stream>>>(score, wsExpE, seq_l, wsA, wsS,
                                         wsCtr);
  combine_kernel<<<B, 256, 0, stream>>>(score, start_tr, end_tr, wsA, wsS,
                                        wsNum, out);
}

// Round 7
// 231.236 us; speedup vs baseline: 1.8968x; 1.8968x over previous
//
#include <hip/hip_runtime.h>
#include <hip/hip_bf16.h>

// CRF NLL + argmax, B=2048, T=1024, K=8.
// p_t = D_t E^T p_{t-1};  E = exp(transitions) staged in ws -> uniform
// s_load -> SGPRs (verified r4/r5: SGPR=112, VGPR=36, no spill).
// NC=64 even-split chunks/batch. Chunk kernel: ONE WAVE PER WORKGROUP,
// 16384 workgroups vs 8192-wave residency -> HW dispatcher backfills as
// short tasks retire (free dynamic load balancing; r4/r5 lesson: a global
// atomic task counter serializes at ~14 ns/op and cost 186 us).
// Batch order shuffled (odd-multiplier bijection) to decorrelate resident
// wave lengths. Private emission loads (L1 broadcast) + private exps: no
// cross-lane ops in the serial chain.
// Combine: block-per-batch LDS tree (6 levels of scale-aware 8x8 products).

namespace {

constexpr int B = 2048;
constexpr int T = 1024;
constexpr int NC = 64;  // chunks per batch

__device__ __forceinline__ float max8(const float* a) {
  return fmaxf(fmaxf(fmaxf(a[0], a[1]), fmaxf(a[2], a[3])),
               fmaxf(fmaxf(a[4], a[5]), fmaxf(a[6], a[7])));
}

// ---------------------------------------------------------------------------
// Kernel 0: init — zero wsNum/out[0], precompute expE.
// ---------------------------------------------------------------------------
__global__ void init_kernel(const float* __restrict__ trans,
                            float* __restrict__ expE,
                            float* __restrict__ ws_num,
                            float* __restrict__ out0) {
  int i = threadIdx.x;
  for (int r = i; r < B; r += 256) ws_num[r] = 0.0f;
  if (i < 64) expE[i] = __expf(trans[i]);
  if (i == 64) *out0 = 0.0f;
}

// ---------------------------------------------------------------------------
// Kernel 1: 4 timesteps/thread: argmax prediction + numerator partials.
// ---------------------------------------------------------------------------
__global__ __launch_bounds__(256) void pred_num_kernel(
    const float* __restrict__ log_p, const float* __restrict__ score,
    const float* __restrict__ trans, const float* __restrict__ start_tr,
    const float* __restrict__ end_tr, const int* __restrict__ tags,
    const int* __restrict__ seq_l, float* __restrict__ out_pred,
    float* __restrict__ ws_num) {
  int tid = blockIdx.x * blockDim.x + threadIdx.x;
  int g0 = tid << 2;
  int b = g0 >> 10;
  int t0 = g0 & (T - 1);
  int L = seq_l[b];

  const float4* lp = reinterpret_cast<const float4*>(log_p) + (g0 << 1);
  float4 u[8];
#pragma unroll
  for (int r = 0; r < 8; ++r) u[r] = lp[r];
  int4 tg4 = *reinterpret_cast<const int4*>(tags + g0);
  int tg[4] = {tg4.x, tg4.y, tg4.z, tg4.w};
  int prev0 = (t0 == 0) ? 0 : tags[g0 - 1];

  float contrib = 0.0f;
#pragma unroll
  for (int r = 0; r < 4; ++r) {
    float v[8] = {u[2 * r].x, u[2 * r].y, u[2 * r].z, u[2 * r].w,
                  u[2 * r + 1].x, u[2 * r + 1].y, u[2 * r + 1].z,
                  u[2 * r + 1].w};
    int best = 0;
    float bv = v[0];
#pragma unroll
    for (int j = 1; j < 8; ++j) {
      if (v[j] > bv) { bv = v[j]; best = j; }
    }
    int t = t0 + r;
    bool act = (t < L);
    out_pred[g0 + r] = act ? (float)best : 0.0f;
    if (act) {
      int tgr = tg[r];
      float csum = score[(size_t)(g0 + r) * 8 + tgr];
      if (t == 0)
        csum += start_tr[tgr];
      else
        csum += trans[((r == 0) ? prev0 : tg[r - 1]) * 8 + tgr];
      if (t == L - 1) csum += end_tr[tgr];
      contrib += csum;
    }
  }
#pragma unroll
  for (int off = 32; off >= 1; off >>= 1) contrib += __shfl_down(contrib, off);
  if ((threadIdx.x & 63) == 0) atomicAdd(&ws_num[b], contrib);
}

// ---------------------------------------------------------------------------
// Kernel 2: chunk transfer matrices. ONE WAVE PER WORKGROUP.
// wave wid: braw = wid>>3, oct = wid&7, b = (braw*1229)&2047 (bijection);
// lane = grp*8+k -> chunk c = oct*8+grp, column k. Even-split bounds.
// ---------------------------------------------------------------------------
__global__ __launch_bounds__(64) void chunk_kernel(
    const float* __restrict__ score, const float* __restrict__ expE,
    const int* __restrict__ seq_l, float* __restrict__ wsA,
    float* __restrict__ wsS) {
  float E[64];
#pragma unroll
  for (int i = 0; i < 64; ++i) E[i] = expE[i];  // uniform -> s_load -> SGPRs

  int wid = blockIdx.x;
  int braw = wid >> 3;
  int oct = wid & 7;
  int b = (int)(((unsigned)braw * 1229u) & 2047u);  // shuffled batch

  int lane = threadIdx.x & 63;
  int grp = lane >> 3;
  int k = lane & 7;
  int c = oct * 8 + grp;

  int S = seq_l[b] - 1;
  int ts = 1 + ((S * c) >> 6);
  int te = 1 + ((S * (c + 1)) >> 6);
  int n = te - ts;

  float a[8];
#pragma unroll
  for (int j = 0; j < 8; ++j) a[j] = (j == k) ? 1.0f : 0.0f;
  float sig = 0.0f;

  const float* sp = score + ((size_t)b * T + ts) * 8;
  float4 nA, nB;
  if (n > 0) {
    nA = *reinterpret_cast<const float4*>(sp);
    nB = *reinterpret_cast<const float4*>(sp + 4);
  }
  for (int it = 0; it < n; ++it) {
    float4 cA = nA, cB = nB;
    if (it + 1 < n) {  // prefetch next step ahead of this step's FMAs
      nA = *reinterpret_cast<const float4*>(sp + 8);
      nB = *reinterpret_cast<const float4*>(sp + 12);
    }
    sp += 8;
    float em[8] = {__expf(cA.x), __expf(cA.y), __expf(cA.z), __expf(cA.w),
                   __expf(cB.x), __expf(cB.y), __expf(cB.z), __expf(cB.w)};
    float na[8];
#pragma unroll
    for (int j = 0; j < 8; ++j) {
      float acc = E[0 * 8 + j] * a[0];
#pragma unroll
      for (int i = 1; i < 8; ++i) acc = fmaf(E[i * 8 + j], a[i], acc);
      na[j] = em[j] * acc;
    }
#pragma unroll
    for (int j = 0; j < 8; ++j) a[j] = na[j];
    if ((it & 7) == 7) {  // rescale every 8 steps (growth <= ~2^10/step)
      float mm = max8(a);
      float r = __builtin_amdgcn_rcpf(mm);
#pragma unroll
      for (int j = 0; j < 8; ++j) a[j] *= r;
      sig += __logf(mm);
    }
  }
  {  // final normalize (n==0 -> identity, mm==1, sig==0)
    float mm = max8(a);
    if (mm > 0.0f) {
      float r = __builtin_amdgcn_rcpf(mm);
#pragma unroll
      for (int j = 0; j < 8; ++j) a[j] *= r;
      sig += __logf(mm);
    }
  }

  float* Ao = wsA + (size_t)(b * NC + c) * 64;
#pragma unroll
  for (int j = 0; j < 8; ++j) Ao[j * 8 + k] = a[j];  // row-major
  wsS[(b * NC + c) * 8 + k] = sig;
}

// ---------------------------------------------------------------------------
// Kernel 3: combine — block per batch, LDS tree of scale-aware products.
// ---------------------------------------------------------------------------
__global__ __launch_bounds__(256) void combine_kernel(
    const float* __restrict__ score, const float* __restrict__ start_tr,
    const float* __restrict__ end_tr, const float* __restrict__ wsA,
    const float* __restrict__ wsS, const float* __restrict__ ws_num,
    float* __restrict__ out_loss) {
  __shared__ float sm[96 * 73];
  int b = blockIdx.x;
  int tid = threadIdx.x;
  const float* Ab = wsA + (size_t)b * NC * 64;
  const float* Sb = wsS + (size_t)b * NC * 8;

#pragma unroll
  for (int r = 0; r < 4; ++r) {
    int vi = tid + r * 256;
    int g = vi * 4;
    int c = g >> 6, rem = g & 63;
    float4 q = reinterpret_cast<const float4*>(Ab)[vi];
    float* dst = &sm[c * 73 + rem];
    dst[0] = q.x; dst[1] = q.y; dst[2] = q.z; dst[3] = q.w;
  }
#pragma unroll
  for (int r = 0; r < 2; ++r) {
    int gi = tid + r * 256;
    sm[(gi >> 3) * 73 + 64 + (gi & 7)] = Sb[gi];
  }
  __syncthreads();

  float* bufB = &sm[64 * 73];
  int p = tid >> 3, k = tid & 7;
#pragma unroll
  for (int lvl = 1; lvl <= 6; ++lvl) {
    int nprod = NC >> lvl;
    float* inb = (lvl & 1) ? sm : bufB;
    float* outb = (lvl & 1) ? bufB : sm;
    if (p < nprod) {
      const float* M0 = inb + (size_t)(2 * p) * 73;      // earlier (right)
      const float* M1 = inb + (size_t)(2 * p + 1) * 73;  // later (left)
      float s1[8];
#pragma unroll
      for (int i = 0; i < 8; ++i) s1[i] = M1[64 + i];
      float m = max8(s1);
      float w[8];
#pragma unroll
      for (int i = 0; i < 8; ++i) w[i] = M0[i * 8 + k] * __expf(s1[i] - m);
      float u[8];
#pragma unroll
      for (int j = 0; j < 8; ++j) {
        float acc = M1[j * 8 + 0] * w[0];
#pragma unroll
        for (int i = 1; i < 8; ++i) acc = fmaf(M1[j * 8 + i], w[i], acc);
        u[j] = acc;
      }
      float mm = fmaxf(max8(u), 1e-37f);
      float rc = __builtin_amdgcn_rcpf(mm);
      float* D = outb + (size_t)p * 73;
#pragma unroll
      for (int j = 0; j < 8; ++j) D[j * 8 + k] = u[j] * rc;
      D[64 + k] = M0[64 + k] + m + __logf(mm);
    }
    __syncthreads();
  }

  if (tid < 8) {
    int j = tid;
    float p0 = __expf(start_tr[j] + score[(size_t)b * T * 8 + j]);
    float m0 = p0;
#pragma unroll
    for (int m = 1; m < 8; m <<= 1) m0 = fmaxf(m0, __shfl_xor(m0, m, 8));
    float p0n = p0 * __builtin_amdgcn_rcpf(m0);
    float p0a[8];
#pragma unroll
    for (int i = 0; i < 8; ++i) p0a[i] = __shfl(p0n, i, 8);
    float sM[8];
#pragma unroll
    for (int i = 0; i < 8; ++i) sM[i] = sm[64 + i];
    float mS = max8(sM);
    float inner = 0.0f;
#pragma unroll
    for (int i = 0; i < 8; ++i)
      inner = fmaf(sm[j * 8 + i], __expf(sM[i] - mS) * p0a[i], inner);
    float term = inner * __expf(end_tr[j]);
#pragma unroll
    for (int m = 1; m < 8; m <<= 1) term += __shfl_xor(term, m, 8);
    if (j == 0) {
      float logz = __logf(m0) + mS + __logf(term);
      atomicAdd(out_loss, (logz - ws_num[b]) * (1.0f / (float)B));
    }
  }
}

}  // namespace

extern "C" void kernel_launch(void* const* d_in, const int* in_sizes, int n_in,
                              void* d_out, int out_size, void* d_ws,
                              size_t ws_size, hipStream_t stream) {
  const float* log_p = (const float*)d_in[0];
  const float* score = (const float*)d_in[1];
  const float* trans = (const float*)d_in[2];
  const float* start_tr = (const float*)d_in[3];
  const float* end_tr = (const float*)d_in[4];
  const int* tags = (const int*)d_in[5];
  const int* seq_l = (const int*)d_in[6];
  float* out = (float*)d_out;  // out[0]=loss, out[1..]=pred_idx

  float* wsA = (float*)d_ws;                  // B*NC*64
  float* wsS = wsA + (size_t)B * NC * 64;     // B*NC*8
  float* wsNum = wsS + (size_t)B * NC * 8;    // B
  float* wsExpE = wsNum + B;                  // 64

  init_kernel<<<1, 256, 0, stream>>>(trans, wsExpE, wsNum, out);
  pred_num_kernel<<<(B * T / 4) / 256, 256, 0, stream>>>(
      log_p, score, trans, start_tr, end_tr, tags, seq_l, out + 1, wsNum);
  chunk_kernel<<<B * NC / 8, 64, 0, stream>>>(score, wsExpE, seq_l, wsA, wsS);
  combine_kernel<<<B, 256, 0, stream>>>(score, start_tr, end_tr, wsA, wsS,
                                        wsNum, out);
}